// Round 2
// baseline (1566.133 us; speedup 1.0000x reference)
//
#include <hip/hip_runtime.h>

// Problem constants (B=8, T=2048 -> NTOK=16384; D=1024, E=8, F=4096, top_k=2)
#define NTOK 16384
#define DDIM 1024
#define FDIM 4096
#define NEXP 8
#define MAXT 136                    // max 256-row tiles: 32768/256 + 8
#define PADPAIRS (MAXT * 256)       // 34816

// Fixed workspace layout (bytes); h + aux are placed dynamically after these.
#define WS_XB      0ull                    // bf16 x       [NTOK][D]      33,554,432
#define WS_WFCB    33554432ull             // bf16 wfc     [E][F][D]      67,108,864
#define WS_WPROJB  100663296ull            // bf16 wproj   [E][D][F]      67,108,864
#define WS_H       167772160ull            // bf16 h       [ct*256][F]    (dynamic)

typedef short bf16x8 __attribute__((ext_vector_type(8)));
typedef float f32x4 __attribute__((ext_vector_type(4)));

__device__ __forceinline__ unsigned short f2bf(float f) {
    unsigned int u = __float_as_uint(f);
    u += 0x7fffu + ((u >> 16) & 1u);   // round to nearest even
    return (unsigned short)(u >> 16);
}

// async global->LDS direct load, 16B per lane. LDS dest = wave-uniform base + lane*16.
__device__ __forceinline__ void gload16(const unsigned short* g, const unsigned short* lds) {
    __builtin_amdgcn_global_load_lds(
        (const __attribute__((address_space(1))) unsigned int*)(unsigned long long)(const void*)g,
        (__attribute__((address_space(3))) unsigned int*)(unsigned int)(unsigned long long)(const void*)lds,
        16, 0, 0);
}

// ---------------- fp32 -> bf16 weight conversion ----------------
__global__ __launch_bounds__(256) void convert_kernel(const float* __restrict__ src,
                                                      unsigned short* __restrict__ dst) {
    int i = blockIdx.x * 256 + threadIdx.x;     // one float4 per thread
    float4 v = ((const float4*)src)[i];
    ushort4 o;
    o.x = f2bf(v.x); o.y = f2bf(v.y); o.z = f2bf(v.z); o.w = f2bf(v.w);
    ((ushort4*)dst)[i] = o;
}

// ---------------- router: logits (fp32), top-2 + softmax gates, x->bf16 ----------------
__global__ __launch_bounds__(256) void router_kernel(const float* __restrict__ x,
                                                     const float* __restrict__ rw,
                                                     unsigned short* __restrict__ xb,
                                                     float* __restrict__ logits,
                                                     int* __restrict__ tok_idx,
                                                     float* __restrict__ tok_gate,
                                                     int* __restrict__ counts) {
    __shared__ float srw[NEXP * DDIM];          // 32 KiB
    __shared__ int scnt[NEXP];
    int tid = threadIdx.x;
    if (tid < NEXP) scnt[tid] = 0;
    for (int i = tid; i < NEXP * DDIM / 4; i += 256)
        ((float4*)srw)[i] = ((const float4*)rw)[i];
    __syncthreads();

    int wave = tid >> 6, lane = tid & 63;
    const float4* srw4 = (const float4*)srw;

    for (int j = 0; j < 4; j++) {
        int t = blockIdx.x * 16 + wave * 4 + j;
        const float4* xr = (const float4*)(x + (size_t)t * DDIM);
        ushort4* xbr = (ushort4*)(xb + (size_t)t * DDIM);

        float acc[NEXP];
#pragma unroll
        for (int e = 0; e < NEXP; e++) acc[e] = 0.f;

#pragma unroll
        for (int i = 0; i < 4; i++) {
            int k4 = i * 64 + lane;
            float4 xv = xr[k4];
            ushort4 o;
            o.x = f2bf(xv.x); o.y = f2bf(xv.y); o.z = f2bf(xv.z); o.w = f2bf(xv.w);
            xbr[k4] = o;
#pragma unroll
            for (int e = 0; e < NEXP; e++) {
                float4 wv = srw4[e * 256 + k4];
                acc[e] += xv.x * wv.x + xv.y * wv.y + xv.z * wv.z + xv.w * wv.w;
            }
        }
#pragma unroll
        for (int off = 1; off < 64; off <<= 1) {
#pragma unroll
            for (int e = 0; e < NEXP; e++) acc[e] += __shfl_xor(acc[e], off);
        }
        if (lane == 0) {
            float v0 = -1e30f, v1 = -1e30f; int i0 = 0, i1 = 0;
#pragma unroll
            for (int e = 0; e < NEXP; e++) {
                float v = acc[e];
                logits[(size_t)t * NEXP + e] = v;
                if (v > v0)      { v1 = v0; i1 = i0; v0 = v; i0 = e; }
                else if (v > v1) { v1 = v;  i1 = e; }
            }
            float d = __expf(v1 - v0);              // <= 1, stable
            float g0 = 1.f / (1.f + d);
            float g1 = d * g0;
            tok_idx[t * 2 + 0] = i0; tok_idx[t * 2 + 1] = i1;
            tok_gate[t * 2 + 0] = g0; tok_gate[t * 2 + 1] = g1;
            atomicAdd(&scnt[i0], 1);
            atomicAdd(&scnt[i1], 1);
        }
    }
    __syncthreads();
    if (tid < NEXP) atomicAdd(&counts[tid], scnt[tid]);
}

// ---------------- segment planning (256-row tiles) + pair-array padding init ----------------
__global__ void seg_plan(const int* __restrict__ counts, int* __restrict__ seg_start,
                         int* __restrict__ tile2e, int* __restrict__ total_tiles,
                         int* __restrict__ pair_token, float* __restrict__ pair_gate) {
    if (threadIdx.x == 0) {
        int cum = 0, tl = 0;
        for (int e = 0; e < NEXP; e++) {
            seg_start[e] = cum;
            int tiles = (counts[e] + 255) >> 8;
            for (int i = 0; i < tiles; i++) tile2e[tl++] = e;
            cum += tiles << 8;
        }
        for (int i = tl; i < MAXT; i++) tile2e[i] = -1;
        *total_tiles = tl;
    }
    for (int i = threadIdx.x; i < PADPAIRS; i += 256) {
        pair_token[i] = 0;
        pair_gate[i] = 0.f;
    }
}

// ---------------- scatter tokens into per-expert segments ----------------
__global__ __launch_bounds__(256) void scatter_k(const int* __restrict__ tok_idx,
                                                 const float* __restrict__ tok_gate,
                                                 const int* __restrict__ seg_start,
                                                 int* __restrict__ cursor,
                                                 int* __restrict__ pair_token,
                                                 float* __restrict__ pair_gate) {
    int t = blockIdx.x * 256 + threadIdx.x;
#pragma unroll
    for (int s = 0; s < 2; s++) {
        int e = tok_idx[t * 2 + s];
        int pos = seg_start[e] + atomicAdd(&cursor[e], 1);
        pair_token[pos] = t;
        pair_gate[pos] = tok_gate[t * 2 + s];
    }
}

// ================= 256x256, BK=64, 8-phase double-buffered MFMA core =================
// (m201/HipKittens schedule re-derived in plain HIP.)
// LDS map (shorts, static 128 KiB):
//   A k-slabs [buf][s][256][32] at (buf)*16384 + (s)*8192   (slab s = k-columns s*32..s*32+31)
//   B tiles   [buf][256][64]    at 32768 + (buf)*16384
// Swizzles (source-preswizzled, read-side matched; evenly bank-spread):
//   A: LDS[r][b] = G[r][(b-(r>>1))&3]  -> read block (quad+(l16>>1))&3
//   B: LDS[r][b] = G[r][b^(r&7)]       -> read block (s*4+quad)^(l16&7)
// Phase p of a K-tile computes C-quadrant (s=p>>1, mhalf=p&1): 16 MFMA per wave.
// Stage slots (iter i computes kt 2i (buf0) / 2i+1 (buf1)):
//   P1: buf1.Aslab1<-kt2i+1  P2: buf0.Bh0<-kt2i+2  P3: buf0.Aslab0  P4: buf0.Bh1 [vmcnt(6)]
//   P5: buf0.Aslab1          P6: buf1.Bh0<-kt2i+3  P7: buf1.Aslab0  P8: buf1.Bh1 [vmcnt(6)]
// Each region is re-staged strictly after its last reader phase (WAR-safe via per-phase
// barriers); vmcnt(6)=3 halves in flight guarantees the next K-tile's 4 halves landed (RAW).

#define STG_A(buf,s,kt) do { \
    gload16(aP0 + (size_t)(kt)*64 + (s)*32, lds + (buf)*16384 + (s)*8192 + (wid*2+0)*512); \
    gload16(aP1 + (size_t)(kt)*64 + (s)*32, lds + (buf)*16384 + (s)*8192 + (wid*2+1)*512); \
} while (0)
#define STG_B(buf,hh,kt) do { \
    gload16(bP + (size_t)((hh)*128+0)*KDIM + (kt)*64, lds + 32768 + (buf)*16384 + (hh)*8192 + (wid*2+0)*512); \
    gload16(bP + (size_t)((hh)*128+8)*KDIM + (kt)*64, lds + 32768 + (buf)*16384 + (hh)*8192 + (wid*2+1)*512); \
} while (0)
#define NOSTG ((void)0)
#define DS_A4(buf,s,mh) do { \
    _Pragma("unroll") \
    for (int m = 0; m < 4; m++) { \
        int row = wm + ((mh)*4+m)*16 + l16; \
        af[m] = *(const bf16x8*)&lds[(buf)*16384 + (s)*8192 + row*32 + (((quad + (l16>>1)) & 3) << 3)]; \
    } \
} while (0)
#define DS_B8(buf) do { \
    _Pragma("unroll") \
    for (int n = 0; n < 4; n++) { \
        int row = wn + n*16 + l16; \
        bfr[n][0] = *(const bf16x8*)&lds[32768 + (buf)*16384 + row*64 + (((quad ^ (l16 & 7))) << 3)]; \
        bfr[n][1] = *(const bf16x8*)&lds[32768 + (buf)*16384 + row*64 + ((((4 + quad) ^ (l16 & 7))) << 3)]; \
    } \
} while (0)
#define MFMA16(s,mh) do { \
    __builtin_amdgcn_s_setprio(1); \
    _Pragma("unroll") \
    for (int m = 0; m < 4; m++) \
        _Pragma("unroll") \
        for (int n = 0; n < 4; n++) \
            acc[(mh)*4+m][n] = __builtin_amdgcn_mfma_f32_16x16x32_bf16(af[m], bfr[n][(s)], acc[(mh)*4+m][n], 0, 0, 0); \
    __builtin_amdgcn_s_setprio(0); \
} while (0)
#define SBAR() do { __builtin_amdgcn_s_barrier(); __builtin_amdgcn_sched_barrier(0); } while (0)
#define WLGKM0() do { asm volatile("s_waitcnt lgkmcnt(0)" ::: "memory"); __builtin_amdgcn_sched_barrier(0); } while (0)
#define PH(buf,s,mh,STG) do { DS_A4(buf,s,mh); STG; SBAR(); WLGKM0(); MFMA16(s,mh); SBAR(); } while (0)
#define PH_F(buf,STG) do { DS_A4(buf,0,0); DS_B8(buf); STG; \
    asm volatile("s_waitcnt lgkmcnt(8)" ::: "memory"); \
    SBAR(); WLGKM0(); MFMA16(0,0); SBAR(); } while (0)
#define PH_V(buf,s,mh,STG,VN) do { DS_A4(buf,s,mh); STG; SBAR(); WLGKM0(); MFMA16(s,mh); \
    asm volatile("s_waitcnt vmcnt(" VN ")" ::: "memory"); SBAR(); } while (0)

template <int KDIM>
__device__ __forceinline__ void mma256(unsigned short* lds,
        const unsigned short* aP0, const unsigned short* aP1, const unsigned short* bP,
        int wid, int lane, f32x4 (&acc)[8][4])
{
    const int l16 = lane & 15, quad = lane >> 4;
    const int wm = (wid >> 2) * 128, wn = (wid & 3) * 64;
    bf16x8 af[4];
    bf16x8 bfr[4][2];
    f32x4 z = {0.f, 0.f, 0.f, 0.f};
#pragma unroll
    for (int i = 0; i < 8; i++)
#pragma unroll
        for (int j = 0; j < 4; j++) acc[i][j] = z;

    // prologue: buf0 <- kt0 (8 loads first!), then buf1 <- kt1 {Bh0, Aslab0, Bh1} (6 loads)
    STG_B(0,0,0); STG_A(0,0,0); STG_B(0,1,0); STG_A(0,1,0);
    __builtin_amdgcn_sched_barrier(0);
    STG_B(1,0,1); STG_A(1,0,1); STG_B(1,1,1);
    __builtin_amdgcn_sched_barrier(0);
    asm volatile("s_waitcnt vmcnt(6)" ::: "memory");   // buf0's 8 loads landed
    __builtin_amdgcn_s_barrier();
    __builtin_amdgcn_sched_barrier(0);

    constexpr int NITER = KDIM / 128;
#pragma unroll 1
    for (int it = 0; it < NITER - 1; ++it) {
        const int kB1 = 2*it + 1, kA2 = 2*it + 2, kB2 = 2*it + 3;
        PH_F(0,       STG_A(1,1,kB1));
        PH  (0,0,1,   STG_B(0,0,kA2));
        PH  (0,1,0,   STG_A(0,0,kA2));
        PH_V(0,1,1,   STG_B(0,1,kA2), "6");
        PH_F(1,       STG_A(0,1,kA2));
        PH  (1,0,1,   STG_B(1,0,kB2));
        PH  (1,1,0,   STG_A(1,0,kB2));
        PH_V(1,1,1,   STG_B(1,1,kB2), "6");
    }
    // final iteration: only buf1's last A-slab still needs staging; drain at P4.
    PH_F(0,       STG_A(1,1,2*NITER-1));
    PH  (0,0,1,   NOSTG);
    PH  (0,1,0,   NOSTG);
    PH_V(0,1,1,   NOSTG, "0");
    PH_F(1,       NOSTG);
    PH  (1,0,1,   NOSTG);
    PH  (1,1,0,   NOSTG);
    PH  (1,1,1,   NOSTG);
}

// ---------------- GEMM1: h = gelu(x_gathered @ wfc[e]^T + bfc[e]) ----------------
// grid = (ct tiles, 16 f-tiles): x-major tile order groups the 16 blocks sharing one
// A-panel onto the same XCD (136 % 8 == 0) for L2 reuse.
__global__ __launch_bounds__(512) void gemm1_kernel(
        const unsigned short* __restrict__ xb, const unsigned short* __restrict__ wfcb,
        const float* __restrict__ bfc, const int* __restrict__ pair_token,
        const int* __restrict__ tile2e, int chunk_base, unsigned short* __restrict__ h)
{
    int tile = chunk_base + blockIdx.x;
    int e = tile2e[tile];
    if (e < 0) return;
    int ftile = blockIdx.y;                     // 0..15
    __shared__ unsigned short lds[65536];       // 128 KiB static
    int tid = threadIdx.x, wid = tid >> 6, lane = tid & 63;

    int gA = ((lane & 3) - ((lane >> 3) & 3)) & 3;
    int gB = (lane & 7) ^ (lane >> 3);
    int arow0 = (wid*2+0)*16 + (lane >> 2);
    int arow1 = (wid*2+1)*16 + (lane >> 2);
    const unsigned short* aP0 = xb + (size_t)pair_token[tile*256 + arow0] * DDIM + gA*8;
    const unsigned short* aP1 = xb + (size_t)pair_token[tile*256 + arow1] * DDIM + gA*8;
    const unsigned short* bP = wfcb + (size_t)e * FDIM * DDIM
                             + (size_t)(ftile*256 + wid*16 + (lane>>3)) * DDIM + gB*8;

    f32x4 acc[8][4];
    mma256<DDIM>(lds, aP0, aP1, bP, wid, lane, acc);

    const int l16 = lane & 15, quad = lane >> 4;
    const int wm = (wid >> 2) * 128, wn = (wid & 3) * 64;
    const float* bfc_e = bfc + e * FDIM + ftile * 256;
    unsigned short* hb = h + (size_t)blockIdx.x * 256 * FDIM + (size_t)ftile * 256;
#pragma unroll
    for (int j = 0; j < 4; j++) {
        int col = wn + j*16 + l16;
        float bias = bfc_e[col];
#pragma unroll
        for (int i = 0; i < 8; i++) {
#pragma unroll
            for (int r = 0; r < 4; r++) {
                int row = wm + i*16 + quad*4 + r;
                float v = acc[i][j][r] + bias;
                v = 0.5f * v * (1.f + erff(v * 0.70710678118654752f));
                hb[(size_t)row * FDIM + col] = f2bf(v);
            }
        }
    }
}

// ---------------- GEMM2: out[token] += (h @ wproj[e]^T + bproj[e]) * gate ----------------
__global__ __launch_bounds__(512) void gemm2_kernel(
        const unsigned short* __restrict__ h, const unsigned short* __restrict__ wprojb,
        const float* __restrict__ bproj, const int* __restrict__ pair_token,
        const float* __restrict__ pair_gate, const int* __restrict__ tile2e,
        int chunk_base, float* __restrict__ out)
{
    int tile = chunk_base + blockIdx.x;
    int e = tile2e[tile];
    if (e < 0) return;
    int dtile = blockIdx.y;                     // 0..3
    __shared__ unsigned short lds[65536];       // 128 KiB static
    int tid = threadIdx.x, wid = tid >> 6, lane = tid & 63;

    int gA = ((lane & 3) - ((lane >> 3) & 3)) & 3;
    int gB = (lane & 7) ^ (lane >> 3);
    const unsigned short* hA = h + (size_t)blockIdx.x * 256 * FDIM;
    const unsigned short* aP0 = hA + (size_t)((wid*2+0)*16 + (lane >> 2)) * FDIM + gA*8;
    const unsigned short* aP1 = hA + (size_t)((wid*2+1)*16 + (lane >> 2)) * FDIM + gA*8;
    const unsigned short* bP = wprojb + (size_t)e * DDIM * FDIM
                             + (size_t)(dtile*256 + wid*16 + (lane>>3)) * FDIM + gB*8;

    f32x4 acc[8][4];
    mma256<FDIM>(lds, aP0, aP1, bP, wid, lane, acc);

    const int l16 = lane & 15, quad = lane >> 4;
    const int wm = (wid >> 2) * 128, wn = (wid & 3) * 64;
    const float* bp_e = bproj + e * DDIM + dtile * 256;
#pragma unroll
    for (int i = 0; i < 8; i++) {
#pragma unroll
        for (int r = 0; r < 4; r++) {
            int row = wm + i*16 + quad*4 + r;
            int tok = pair_token[tile*256 + row];
            float gate = pair_gate[tile*256 + row];
            float* orow = out + (size_t)tok * DDIM + dtile * 256;
#pragma unroll
            for (int j = 0; j < 4; j++) {
                int col = wn + j*16 + l16;
                atomicAdd(&orow[col], (acc[i][j][r] + bp_e[col]) * gate);
            }
        }
    }
}

// ---------------- LayerNorm (in-place on out) ----------------
__global__ __launch_bounds__(256) void ln_kernel(float* __restrict__ out,
                                                 const float* __restrict__ g,
                                                 const float* __restrict__ b) {
    __shared__ float s1[4], s2[4];
    int t = blockIdx.x, tid = threadIdx.x;
    float* row = out + (size_t)t * DDIM;
    float4 v = ((const float4*)row)[tid];
    float sum = v.x + v.y + v.z + v.w;
    float sq = v.x * v.x + v.y * v.y + v.z * v.z + v.w * v.w;
#pragma unroll
    for (int off = 32; off > 0; off >>= 1) {
        sum += __shfl_down(sum, off);
        sq  += __shfl_down(sq, off);
    }
    int wave = tid >> 6, lane = tid & 63;
    if (lane == 0) { s1[wave] = sum; s2[wave] = sq; }
    __syncthreads();
    float tot = s1[0] + s1[1] + s1[2] + s1[3];
    float totsq = s2[0] + s2[1] + s2[2] + s2[3];
    float mu = tot * (1.f / DDIM);
    float var = totsq * (1.f / DDIM) - mu * mu;
    float rs = rsqrtf(var + 1e-5f);
    float4 gv = ((const float4*)g)[tid];
    float4 bv = ((const float4*)b)[tid];
    float4 o;
    o.x = (v.x - mu) * rs * gv.x + bv.x;
    o.y = (v.y - mu) * rs * gv.y + bv.y;
    o.z = (v.z - mu) * rs * gv.z + bv.z;
    o.w = (v.w - mu) * rs * gv.w + bv.w;
    ((float4*)row)[tid] = o;
}

extern "C" void kernel_launch(void* const* d_in, const int* in_sizes, int n_in,
                              void* d_out, int out_size, void* d_ws, size_t ws_size,
                              hipStream_t stream) {
    const float* x   = (const float*)d_in[0];
    const float* rw  = (const float*)d_in[1];
    const float* wfc = (const float*)d_in[2];
    const float* bfc = (const float*)d_in[3];
    const float* wpr = (const float*)d_in[4];
    const float* bpr = (const float*)d_in[5];
    const float* lng = (const float*)d_in[6];
    const float* lnb = (const float*)d_in[7];

    float* out = (float*)d_out;                       // [16384,1024]
    float* logits = out + (size_t)NTOK * DDIM;        // [16384,8]

    char* ws = (char*)d_ws;
    unsigned short* xb     = (unsigned short*)(ws + WS_XB);
    unsigned short* wfcb   = (unsigned short*)(ws + WS_WFCB);
    unsigned short* wprojb = (unsigned short*)(ws + WS_WPROJB);
    unsigned short* hbuf   = (unsigned short*)(ws + WS_H);

    // Largest chunk (256-row h tiles) that fits in ws; ws_size fixed -> capture-safe.
    size_t aux_bytes = (size_t)PADPAIRS * 8 + (size_t)NTOK * 16 + 4096;
    int ct = 34;                                       // 4 chunks fallback
    if (ws_size >= WS_H + (size_t)136 * 256 * FDIM * 2 + aux_bytes)      ct = 136;
    else if (ws_size >= WS_H + (size_t)68 * 256 * FDIM * 2 + aux_bytes)  ct = 68;
    int nchunks = MAXT / ct;

    char* aux = ws + WS_H + (size_t)ct * 256 * FDIM * 2;
    int*   ptok  = (int*)aux;
    float* pgate = (float*)(aux + (size_t)PADPAIRS * 4);
    int*   tidx  = (int*)(aux + (size_t)PADPAIRS * 8);
    float* tgate = (float*)(aux + (size_t)PADPAIRS * 8 + (size_t)NTOK * 8);
    int*   meta  = (int*)(aux + (size_t)PADPAIRS * 8 + (size_t)NTOK * 16);
    int* counts = meta;          // 8
    int* cursor = meta + 8;      // 8
    int* segs   = meta + 16;     // 8
    int* total  = meta + 24;     // 1
    int* tile2e = meta + 32;     // MAXT

    hipMemsetAsync(out, 0, (size_t)NTOK * DDIM * sizeof(float), stream);
    hipMemsetAsync(meta, 0, 64, stream);

    convert_kernel<<<(NEXP * FDIM * DDIM) / 4 / 256, 256, 0, stream>>>(wfc, wfcb);
    convert_kernel<<<(NEXP * DDIM * FDIM) / 4 / 256, 256, 0, stream>>>(wpr, wprojb);
    router_kernel<<<NTOK / 16, 256, 0, stream>>>(x, rw, xb, logits, tidx, tgate, counts);
    seg_plan<<<1, 256, 0, stream>>>(counts, segs, tile2e, total, ptok, pgate);
    scatter_k<<<NTOK / 256, 256, 0, stream>>>(tidx, tgate, segs, cursor, ptok, pgate);

    for (int c = 0; c < nchunks; c++) {
        gemm1_kernel<<<dim3(ct, FDIM / 256), 512, 0, stream>>>(
            xb, wfcb, bfc, ptok, tile2e, c * ct, hbuf);
        gemm2_kernel<<<dim3(ct, DDIM / 256), 512, 0, stream>>>(
            hbuf, wprojb, bpr, ptok, pgate, tile2e, c * ct, out);
    }
    ln_kernel<<<NTOK, 256, 0, stream>>>(out, lng, lnb);
}

// Round 3
// 1343.134 us; speedup vs baseline: 1.1660x; 1.1660x over previous
//
#include <hip/hip_runtime.h>

// Problem constants (B=8, T=2048 -> NTOK=16384; D=1024, E=8, F=4096, top_k=2)
#define NTOK 16384
#define DDIM 1024
#define FDIM 4096
#define NEXP 8
#define PADPAIRS 33792          // 264 * 128 (worst-case 128-padded segments)
#define MAXTILES 264

// Fixed workspace layout (bytes); h + aux are placed dynamically after these.
#define WS_XB      0ull                    // bf16 x       [NTOK][D]      33,554,432
#define WS_WFCB    33554432ull             // bf16 wfc     [E][F][D]      67,108,864
#define WS_WPROJB  100663296ull            // bf16 wproj   [E][D][F]      67,108,864
#define WS_H       167772160ull            // bf16 h       [ct*128][F]    (dynamic)

typedef short bf16x8 __attribute__((ext_vector_type(8)));
typedef float f32x4 __attribute__((ext_vector_type(4)));

__device__ __forceinline__ unsigned short f2bf(float f) {
    unsigned int u = __float_as_uint(f);
    u += 0x7fffu + ((u >> 16) & 1u);   // round to nearest even
    return (unsigned short)(u >> 16);
}

// CK-style async global->LDS direct load, 16B per lane.
// LDS dest = wave-uniform base + lane*16; global addr is per-lane.
__device__ __forceinline__ void gload16(const unsigned short* g, const unsigned short* lds) {
    __builtin_amdgcn_global_load_lds(
        (const __attribute__((address_space(1))) unsigned int*)(unsigned long long)(const void*)g,
        (__attribute__((address_space(3))) unsigned int*)(unsigned int)(unsigned long long)(const void*)lds,
        16, 0, 0);
}

// ---------------- fp32 -> bf16 weight conversion ----------------
__global__ __launch_bounds__(256) void convert_kernel(const float* __restrict__ src,
                                                      unsigned short* __restrict__ dst) {
    int i = blockIdx.x * 256 + threadIdx.x;     // one float4 per thread
    float4 v = ((const float4*)src)[i];
    ushort4 o;
    o.x = f2bf(v.x); o.y = f2bf(v.y); o.z = f2bf(v.z); o.w = f2bf(v.w);
    ((ushort4*)dst)[i] = o;
}

// ---------------- router: logits (fp32), top-2 + softmax gates, x->bf16 ----------------
__global__ __launch_bounds__(256) void router_kernel(const float* __restrict__ x,
                                                     const float* __restrict__ rw,
                                                     unsigned short* __restrict__ xb,
                                                     float* __restrict__ logits,
                                                     int* __restrict__ tok_idx,
                                                     float* __restrict__ tok_gate,
                                                     int* __restrict__ counts) {
    __shared__ float srw[NEXP * DDIM];          // 32 KiB
    __shared__ int scnt[NEXP];
    int tid = threadIdx.x;
    if (tid < NEXP) scnt[tid] = 0;
    for (int i = tid; i < NEXP * DDIM / 4; i += 256)
        ((float4*)srw)[i] = ((const float4*)rw)[i];
    __syncthreads();

    int wave = tid >> 6, lane = tid & 63;
    const float4* srw4 = (const float4*)srw;

    for (int j = 0; j < 4; j++) {
        int t = blockIdx.x * 16 + wave * 4 + j;
        const float4* xr = (const float4*)(x + (size_t)t * DDIM);
        ushort4* xbr = (ushort4*)(xb + (size_t)t * DDIM);

        float acc[NEXP];
#pragma unroll
        for (int e = 0; e < NEXP; e++) acc[e] = 0.f;

#pragma unroll
        for (int i = 0; i < 4; i++) {
            int k4 = i * 64 + lane;
            float4 xv = xr[k4];
            ushort4 o;
            o.x = f2bf(xv.x); o.y = f2bf(xv.y); o.z = f2bf(xv.z); o.w = f2bf(xv.w);
            xbr[k4] = o;
#pragma unroll
            for (int e = 0; e < NEXP; e++) {
                float4 wv = srw4[e * 256 + k4];
                acc[e] += xv.x * wv.x + xv.y * wv.y + xv.z * wv.z + xv.w * wv.w;
            }
        }
#pragma unroll
        for (int off = 1; off < 64; off <<= 1) {
#pragma unroll
            for (int e = 0; e < NEXP; e++) acc[e] += __shfl_xor(acc[e], off);
        }
        if (lane == 0) {
            float v0 = -1e30f, v1 = -1e30f; int i0 = 0, i1 = 0;
#pragma unroll
            for (int e = 0; e < NEXP; e++) {
                float v = acc[e];
                logits[(size_t)t * NEXP + e] = v;
                if (v > v0)      { v1 = v0; i1 = i0; v0 = v; i0 = e; }
                else if (v > v1) { v1 = v;  i1 = e; }
            }
            float d = __expf(v1 - v0);              // <= 1, stable
            float g0 = 1.f / (1.f + d);
            float g1 = d * g0;
            tok_idx[t * 2 + 0] = i0; tok_idx[t * 2 + 1] = i1;
            tok_gate[t * 2 + 0] = g0; tok_gate[t * 2 + 1] = g1;
            atomicAdd(&scnt[i0], 1);
            atomicAdd(&scnt[i1], 1);
        }
    }
    __syncthreads();
    if (tid < NEXP) atomicAdd(&counts[tid], scnt[tid]);
}

// ---------------- segment planning + pair-array padding init ----------------
__global__ void seg_plan(const int* __restrict__ counts, int* __restrict__ seg_start,
                         int* __restrict__ tile2e, int* __restrict__ total_tiles,
                         int* __restrict__ pair_token, float* __restrict__ pair_gate) {
    if (threadIdx.x == 0) {
        int cum = 0, tl = 0;
        for (int e = 0; e < NEXP; e++) {
            seg_start[e] = cum;
            int tiles = (counts[e] + 127) >> 7;
            for (int i = 0; i < tiles; i++) tile2e[tl++] = e;
            cum += tiles << 7;
        }
        for (int i = tl; i < MAXTILES; i++) tile2e[i] = -1;
        *total_tiles = tl;
    }
    for (int i = threadIdx.x; i < PADPAIRS; i += 256) {
        pair_token[i] = 0;
        pair_gate[i] = 0.f;
    }
}

// ---------------- scatter tokens into per-expert segments ----------------
__global__ __launch_bounds__(256) void scatter_k(const int* __restrict__ tok_idx,
                                                 const float* __restrict__ tok_gate,
                                                 const int* __restrict__ seg_start,
                                                 int* __restrict__ cursor,
                                                 int* __restrict__ pair_token,
                                                 float* __restrict__ pair_gate) {
    int t = blockIdx.x * 256 + threadIdx.x;
#pragma unroll
    for (int s = 0; s < 2; s++) {
        int e = tok_idx[t * 2 + s];
        int pos = seg_start[e] + atomicAdd(&cursor[e], 1);
        pair_token[pos] = t;
        pair_gate[pos] = tok_gate[t * 2 + s];
    }
}

// ---------------- GEMM1: h = gelu(x_gathered @ wfc[e]^T + bfc[e]) ----------------
// 128x128 tile, K=D=1024, BK=64, global_load_lds staging, XOR-swizzled LDS.
// LDS 32 KB; __launch_bounds__(256,3) caps unified regs at ~170 -> 3 blocks/CU
// (m97 operating point: 164 regs, 3 waves/SIMD, MfmaUtil 37%).
__global__ __launch_bounds__(256, 3) void gemm1_kernel(const unsigned short* __restrict__ xb,
                                                    const unsigned short* __restrict__ wfcb,
                                                    const float* __restrict__ bfc,
                                                    const int* __restrict__ pair_token,
                                                    const int* __restrict__ tile2e,
                                                    int chunk_base,
                                                    unsigned short* __restrict__ h) {
    int tile = chunk_base + blockIdx.y;
    int e = tile2e[tile];
    if (e < 0) return;
    int ftile = blockIdx.x;                      // 0..31

    __shared__ unsigned short sA[128 * 64];      // no pad (global_load_lds constraint)
    __shared__ unsigned short sB[128 * 64];      // total 32768 B

    int tid = threadIdx.x;
    int wave = tid >> 6, lane = tid & 63;
    int lrow = lane >> 3;                        // 0..7
    int kblk = (lane & 7) ^ lrow;                // swizzled source k-block

    const unsigned short* wB = wfcb + (size_t)e * FDIM * DDIM + (size_t)ftile * 128 * DDIM;
    const unsigned short* aBase[4];
    const unsigned short* bBase[4];
#pragma unroll
    for (int t = 0; t < 4; t++) {
        int row = wave * 32 + t * 8 + lrow;
        aBase[t] = xb + (size_t)pair_token[tile * 128 + row] * DDIM + kblk * 8;
        bBase[t] = wB + (size_t)row * DDIM + kblk * 8;
    }

    f32x4 zero = {0.f, 0.f, 0.f, 0.f};
    f32x4 acc[4][4];
#pragma unroll
    for (int i = 0; i < 4; i++)
#pragma unroll
        for (int j = 0; j < 4; j++) acc[i][j] = zero;

    int wm = (wave >> 1) * 64, wn = (wave & 1) * 64;
    int quad = lane >> 4, l16 = lane & 15;
    int r7 = l16 & 7;

    for (int k0 = 0; k0 < DDIM; k0 += 64) {
#pragma unroll
        for (int t = 0; t < 4; t++) {
            gload16(aBase[t], &sA[(wave * 32 + t * 8) * 64]);
            gload16(bBase[t], &sB[(wave * 32 + t * 8) * 64]);
            aBase[t] += 64; bBase[t] += 64;
        }
        __syncthreads();
#pragma unroll
        for (int ks = 0; ks < 64; ks += 32) {
            int g = (ks >> 3) + quad;            // global k-block 0..7
            bf16x8 af[4], bfr[4];
#pragma unroll
            for (int i = 0; i < 4; i++) {
                int row = wm + i * 16 + l16;
                af[i] = *(const bf16x8*)&sA[row * 64 + ((g ^ r7) << 3)];
            }
#pragma unroll
            for (int j = 0; j < 4; j++) {
                int row = wn + j * 16 + l16;
                bfr[j] = *(const bf16x8*)&sB[row * 64 + ((g ^ r7) << 3)];
            }
#pragma unroll
            for (int i = 0; i < 4; i++)
#pragma unroll
                for (int j = 0; j < 4; j++)
                    acc[i][j] = __builtin_amdgcn_mfma_f32_16x16x32_bf16(af[i], bfr[j], acc[i][j], 0, 0, 0);
        }
        __syncthreads();
    }

    // epilogue: bias + exact gelu -> bf16 h (chunk-local rows)
    unsigned short* hrow_base = h + (size_t)blockIdx.y * 128 * FDIM;
#pragma unroll
    for (int i = 0; i < 4; i++) {
#pragma unroll
        for (int j = 0; j < 4; j++) {
            int col = wn + j * 16 + l16;
            int f = ftile * 128 + col;
            float bias = bfc[e * FDIM + f];
#pragma unroll
            for (int r = 0; r < 4; r++) {
                int row = wm + i * 16 + quad * 4 + r;
                float v = acc[i][j][r] + bias;
                v = 0.5f * v * (1.f + erff(v * 0.70710678118654752f));
                hrow_base[(size_t)row * FDIM + f] = f2bf(v);
            }
        }
    }
}

// ---------------- GEMM2: out[token] += (h @ wproj[e]^T + bproj[e]) * gate ----------------
// 128x128 tile, K=F=4096, BK=64, global_load_lds staging, XOR-swizzled LDS.
__global__ __launch_bounds__(256, 3) void gemm2_kernel(const unsigned short* __restrict__ h,
                                                    const unsigned short* __restrict__ wprojb,
                                                    const float* __restrict__ bproj,
                                                    const int* __restrict__ pair_token,
                                                    const float* __restrict__ pair_gate,
                                                    const int* __restrict__ tile2e,
                                                    int chunk_base,
                                                    float* __restrict__ out) {
    int tile = chunk_base + blockIdx.y;
    int e = tile2e[tile];
    if (e < 0) return;
    int dtile = blockIdx.x;                      // 0..7

    __shared__ unsigned short sA[128 * 64];
    __shared__ unsigned short sB[128 * 64];      // total 32768 B

    int tid = threadIdx.x;
    int wave = tid >> 6, lane = tid & 63;
    int lrow = lane >> 3;
    int kblk = (lane & 7) ^ lrow;

    const unsigned short* hA = h + (size_t)blockIdx.y * 128 * FDIM;
    const unsigned short* wB = wprojb + (size_t)e * DDIM * FDIM + (size_t)dtile * 128 * FDIM;
    const unsigned short* aBase[4];
    const unsigned short* bBase[4];
#pragma unroll
    for (int t = 0; t < 4; t++) {
        int row = wave * 32 + t * 8 + lrow;
        aBase[t] = hA + (size_t)row * FDIM + kblk * 8;
        bBase[t] = wB + (size_t)row * FDIM + kblk * 8;
    }

    f32x4 zero = {0.f, 0.f, 0.f, 0.f};
    f32x4 acc[4][4];
#pragma unroll
    for (int i = 0; i < 4; i++)
#pragma unroll
        for (int j = 0; j < 4; j++) acc[i][j] = zero;

    int wm = (wave >> 1) * 64, wn = (wave & 1) * 64;
    int quad = lane >> 4, l16 = lane & 15;
    int r7 = l16 & 7;

    for (int k0 = 0; k0 < FDIM; k0 += 64) {
#pragma unroll
        for (int t = 0; t < 4; t++) {
            gload16(aBase[t], &sA[(wave * 32 + t * 8) * 64]);
            gload16(bBase[t], &sB[(wave * 32 + t * 8) * 64]);
            aBase[t] += 64; bBase[t] += 64;
        }
        __syncthreads();
#pragma unroll
        for (int ks = 0; ks < 64; ks += 32) {
            int g = (ks >> 3) + quad;
            bf16x8 af[4], bfr[4];
#pragma unroll
            for (int i = 0; i < 4; i++) {
                int row = wm + i * 16 + l16;
                af[i] = *(const bf16x8*)&sA[row * 64 + ((g ^ r7) << 3)];
            }
#pragma unroll
            for (int j = 0; j < 4; j++) {
                int row = wn + j * 16 + l16;
                bfr[j] = *(const bf16x8*)&sB[row * 64 + ((g ^ r7) << 3)];
            }
#pragma unroll
            for (int i = 0; i < 4; i++)
#pragma unroll
                for (int j = 0; j < 4; j++)
                    acc[i][j] = __builtin_amdgcn_mfma_f32_16x16x32_bf16(af[i], bfr[j], acc[i][j], 0, 0, 0);
        }
        __syncthreads();
    }

    // epilogue: bias, gate, atomic scatter-add into out (exactly 2 adds/element)
#pragma unroll
    for (int i = 0; i < 4; i++) {
#pragma unroll
        for (int j = 0; j < 4; j++) {
            int col = wn + j * 16 + l16;
            int d = dtile * 128 + col;
            float bias = bproj[e * DDIM + d];
#pragma unroll
            for (int r = 0; r < 4; r++) {
                int row = wm + i * 16 + quad * 4 + r;
                int tok = pair_token[tile * 128 + row];     // L1-cached
                float gate = pair_gate[tile * 128 + row];
                float v = (acc[i][j][r] + bias) * gate;
                atomicAdd(&out[(size_t)tok * DDIM + d], v);
            }
        }
    }
}

// ---------------- LayerNorm (in-place on out) ----------------
__global__ __launch_bounds__(256) void ln_kernel(float* __restrict__ out,
                                                 const float* __restrict__ g,
                                                 const float* __restrict__ b) {
    __shared__ float s1[4], s2[4];
    int t = blockIdx.x, tid = threadIdx.x;
    float* row = out + (size_t)t * DDIM;
    float4 v = ((const float4*)row)[tid];
    float sum = v.x + v.y + v.z + v.w;
    float sq = v.x * v.x + v.y * v.y + v.z * v.z + v.w * v.w;
#pragma unroll
    for (int off = 32; off > 0; off >>= 1) {
        sum += __shfl_down(sum, off);
        sq  += __shfl_down(sq, off);
    }
    int wave = tid >> 6, lane = tid & 63;
    if (lane == 0) { s1[wave] = sum; s2[wave] = sq; }
    __syncthreads();
    float tot = s1[0] + s1[1] + s1[2] + s1[3];
    float totsq = s2[0] + s2[1] + s2[2] + s2[3];
    float mu = tot * (1.f / DDIM);
    float var = totsq * (1.f / DDIM) - mu * mu;
    float rs = rsqrtf(var + 1e-5f);
    float4 gv = ((const float4*)g)[tid];
    float4 bv = ((const float4*)b)[tid];
    float4 o;
    o.x = (v.x - mu) * rs * gv.x + bv.x;
    o.y = (v.y - mu) * rs * gv.y + bv.y;
    o.z = (v.z - mu) * rs * gv.z + bv.z;
    o.w = (v.w - mu) * rs * gv.w + bv.w;
    ((float4*)row)[tid] = o;
}

extern "C" void kernel_launch(void* const* d_in, const int* in_sizes, int n_in,
                              void* d_out, int out_size, void* d_ws, size_t ws_size,
                              hipStream_t stream) {
    const float* x   = (const float*)d_in[0];
    const float* rw  = (const float*)d_in[1];
    const float* wfc = (const float*)d_in[2];
    const float* bfc = (const float*)d_in[3];
    const float* wpr = (const float*)d_in[4];
    const float* bpr = (const float*)d_in[5];
    const float* lng = (const float*)d_in[6];
    const float* lnb = (const float*)d_in[7];

    float* out = (float*)d_out;                       // [16384,1024]
    float* logits = out + (size_t)NTOK * DDIM;        // [16384,8]

    char* ws = (char*)d_ws;
    unsigned short* xb     = (unsigned short*)(ws + WS_XB);
    unsigned short* wfcb   = (unsigned short*)(ws + WS_WFCB);
    unsigned short* wprojb = (unsigned short*)(ws + WS_WPROJB);
    unsigned short* hbuf   = (unsigned short*)(ws + WS_H);

    // Pick the largest chunk size (h tiles) that fits in ws. ws_size is fixed
    // across calls, so this branch is graph-capture safe.
    size_t aux_bytes = (size_t)PADPAIRS * 8 + (size_t)NTOK * 16 + 4096;
    int ct = 66;                                      // fallback (4 chunks, known-fit)
    if (ws_size >= WS_H + (size_t)264 * 128 * FDIM * 2 + aux_bytes)      ct = 264;
    else if (ws_size >= WS_H + (size_t)132 * 128 * FDIM * 2 + aux_bytes) ct = 132;
    int nchunks = MAXTILES / ct;

    char* aux = ws + WS_H + (size_t)ct * 128 * FDIM * 2;
    int*   ptok  = (int*)aux;
    float* pgate = (float*)(aux + (size_t)PADPAIRS * 4);
    int*   tidx  = (int*)(aux + (size_t)PADPAIRS * 8);
    float* tgate = (float*)(aux + (size_t)PADPAIRS * 8 + (size_t)NTOK * 8);
    int*   meta  = (int*)(aux + (size_t)PADPAIRS * 8 + (size_t)NTOK * 16);
    int* counts = meta;          // 8
    int* cursor = meta + 8;      // 8
    int* segs   = meta + 16;     // 8
    int* total  = meta + 24;     // 1
    int* tile2e = meta + 32;     // 264

    hipMemsetAsync(out, 0, (size_t)NTOK * DDIM * sizeof(float), stream);
    hipMemsetAsync(meta, 0, 64, stream);

    convert_kernel<<<(NEXP * FDIM * DDIM) / 4 / 256, 256, 0, stream>>>(wfc, wfcb);
    convert_kernel<<<(NEXP * DDIM * FDIM) / 4 / 256, 256, 0, stream>>>(wpr, wprojb);
    router_kernel<<<NTOK / 16, 256, 0, stream>>>(x, rw, xb, logits, tidx, tgate, counts);
    seg_plan<<<1, 256, 0, stream>>>(counts, segs, tile2e, total, ptok, pgate);
    scatter_k<<<NTOK / 256, 256, 0, stream>>>(tidx, tgate, segs, cursor, ptok, pgate);

    for (int c = 0; c < nchunks; c++) {
        gemm1_kernel<<<dim3(FDIM / 128, ct), 256, 0, stream>>>(
            xb, wfcb, bfc, ptok, tile2e, c * ct, hbuf);
        gemm2_kernel<<<dim3(DDIM / 128, ct), 256, 0, stream>>>(
            hbuf, wprojb, bpr, ptok, pgate, tile2e, c * ct, out);
    }
    ln_kernel<<<NTOK, 256, 0, stream>>>(out, lng, lnb);
}

// Round 4
// 1164.864 us; speedup vs baseline: 1.3445x; 1.1530x over previous
//
#include <hip/hip_runtime.h>

// Problem constants (B=8, T=2048 -> NTOK=16384; D=1024, E=8, F=4096, top_k=2)
#define NTOK 16384
#define DDIM 1024
#define FDIM 4096
#define NEXP 8
#define PADPAIRS 33792          // 264 * 128 (worst-case 128-padded segments)
#define MAXTILES 264

// Fixed workspace layout (bytes); h + aux are placed dynamically after these.
#define WS_XB      0ull                    // bf16 x       [NTOK][D]      33,554,432
#define WS_WFCB    33554432ull             // bf16 wfc     [E][F][D]      67,108,864
#define WS_WPROJB  100663296ull            // bf16 wproj   [E][D][F]      67,108,864
#define WS_H       167772160ull            // bf16 h       [ct*128][F]    (dynamic)

typedef short bf16x8 __attribute__((ext_vector_type(8)));
typedef float f32x4 __attribute__((ext_vector_type(4)));

__device__ __forceinline__ unsigned short f2bf(float f) {
    unsigned int u = __float_as_uint(f);
    u += 0x7fffu + ((u >> 16) & 1u);   // round to nearest even
    return (unsigned short)(u >> 16);
}

// CK-style async global->LDS direct load, 16B per lane.
// LDS dest = wave-uniform base + lane*16; global addr is per-lane.
__device__ __forceinline__ void gload16(const unsigned short* g, const unsigned short* lds) {
    __builtin_amdgcn_global_load_lds(
        (const __attribute__((address_space(1))) unsigned int*)(unsigned long long)(const void*)g,
        (__attribute__((address_space(3))) unsigned int*)(unsigned int)(unsigned long long)(const void*)lds,
        16, 0, 0);
}

#define SCHED0() __builtin_amdgcn_sched_barrier(0)

// ---------------- fp32 -> bf16 weight conversion ----------------
__global__ __launch_bounds__(256) void convert_kernel(const float* __restrict__ src,
                                                      unsigned short* __restrict__ dst) {
    int i = blockIdx.x * 256 + threadIdx.x;     // one float4 per thread
    float4 v = ((const float4*)src)[i];
    ushort4 o;
    o.x = f2bf(v.x); o.y = f2bf(v.y); o.z = f2bf(v.z); o.w = f2bf(v.w);
    ((ushort4*)dst)[i] = o;
}

// ---------------- router: logits (fp32), top-2 + softmax gates, x->bf16 ----------------
// counts is padded: counts[e*16] (64 B apart) to avoid hot-cacheline atomics.
__global__ __launch_bounds__(256) void router_kernel(const float* __restrict__ x,
                                                     const float* __restrict__ rw,
                                                     unsigned short* __restrict__ xb,
                                                     float* __restrict__ logits,
                                                     int* __restrict__ tok_idx,
                                                     float* __restrict__ tok_gate,
                                                     int* __restrict__ counts) {
    __shared__ float srw[NEXP * DDIM];          // 32 KiB
    __shared__ int scnt[NEXP];
    int tid = threadIdx.x;
    if (tid < NEXP) scnt[tid] = 0;
    for (int i = tid; i < NEXP * DDIM / 4; i += 256)
        ((float4*)srw)[i] = ((const float4*)rw)[i];
    __syncthreads();

    int wave = tid >> 6, lane = tid & 63;
    const float4* srw4 = (const float4*)srw;

    for (int j = 0; j < 4; j++) {
        int t = blockIdx.x * 16 + wave * 4 + j;
        const float4* xr = (const float4*)(x + (size_t)t * DDIM);
        ushort4* xbr = (ushort4*)(xb + (size_t)t * DDIM);

        float acc[NEXP];
#pragma unroll
        for (int e = 0; e < NEXP; e++) acc[e] = 0.f;

#pragma unroll
        for (int i = 0; i < 4; i++) {
            int k4 = i * 64 + lane;
            float4 xv = xr[k4];
            ushort4 o;
            o.x = f2bf(xv.x); o.y = f2bf(xv.y); o.z = f2bf(xv.z); o.w = f2bf(xv.w);
            xbr[k4] = o;
#pragma unroll
            for (int e = 0; e < NEXP; e++) {
                float4 wv = srw4[e * 256 + k4];
                acc[e] += xv.x * wv.x + xv.y * wv.y + xv.z * wv.z + xv.w * wv.w;
            }
        }
#pragma unroll
        for (int off = 1; off < 64; off <<= 1) {
#pragma unroll
            for (int e = 0; e < NEXP; e++) acc[e] += __shfl_xor(acc[e], off);
        }
        if (lane == 0) {
            float v0 = -1e30f, v1 = -1e30f; int i0 = 0, i1 = 0;
#pragma unroll
            for (int e = 0; e < NEXP; e++) {
                float v = acc[e];
                logits[(size_t)t * NEXP + e] = v;
                if (v > v0)      { v1 = v0; i1 = i0; v0 = v; i0 = e; }
                else if (v > v1) { v1 = v;  i1 = e; }
            }
            float d = __expf(v1 - v0);              // <= 1, stable
            float g0 = 1.f / (1.f + d);
            float g1 = d * g0;
            tok_idx[t * 2 + 0] = i0; tok_idx[t * 2 + 1] = i1;
            tok_gate[t * 2 + 0] = g0; tok_gate[t * 2 + 1] = g1;
            atomicAdd(&scnt[i0], 1);
            atomicAdd(&scnt[i1], 1);
        }
    }
    __syncthreads();
    if (tid < NEXP) atomicAdd(&counts[tid * 16], scnt[tid]);
}

// ---------------- segment planning + pair-array padding init ----------------
__global__ void seg_plan(const int* __restrict__ counts, int* __restrict__ seg_start,
                         int* __restrict__ tile2e, int* __restrict__ total_tiles,
                         int* __restrict__ pair_token, float* __restrict__ pair_gate) {
    if (threadIdx.x == 0) {
        int cum = 0, tl = 0;
        for (int e = 0; e < NEXP; e++) {
            seg_start[e] = cum;
            int tiles = (counts[e * 16] + 127) >> 7;
            for (int i = 0; i < tiles; i++) tile2e[tl++] = e;
            cum += tiles << 7;
        }
        for (int i = tl; i < MAXTILES; i++) tile2e[i] = -1;
        *total_tiles = tl;
    }
    for (int i = threadIdx.x; i < PADPAIRS; i += 256) {
        pair_token[i] = 0;
        pair_gate[i] = 0.f;
    }
}

// ---------------- scatter tokens into per-expert segments ----------------
// Block-aggregated: LDS ranks + 8 padded global atomics per block (vs 512
// same-cacheline device atomics).
__global__ __launch_bounds__(256) void scatter_k(const int* __restrict__ tok_idx,
                                                 const float* __restrict__ tok_gate,
                                                 const int* __restrict__ seg_start,
                                                 int* __restrict__ cursor,
                                                 int* __restrict__ pair_token,
                                                 float* __restrict__ pair_gate) {
    __shared__ int lcnt[NEXP];
    __shared__ int lbase[NEXP];
    int tid = threadIdx.x;
    if (tid < NEXP) lcnt[tid] = 0;
    __syncthreads();
    int t = blockIdx.x * 256 + tid;
    int e0 = tok_idx[t * 2 + 0], e1 = tok_idx[t * 2 + 1];
    float g0 = tok_gate[t * 2 + 0], g1 = tok_gate[t * 2 + 1];
    int r0 = atomicAdd(&lcnt[e0], 1);
    int r1 = atomicAdd(&lcnt[e1], 1);
    __syncthreads();
    if (tid < NEXP) lbase[tid] = atomicAdd(&cursor[tid * 16], lcnt[tid]);
    __syncthreads();
    int p0 = seg_start[e0] + lbase[e0] + r0;
    int p1 = seg_start[e1] + lbase[e1] + r1;
    pair_token[p0] = t; pair_gate[p0] = g0;
    pair_token[p1] = t; pair_gate[p1] = g1;
}

// ---------------- GEMM1: h = gelu(x_gathered @ wfc[e]^T + bfc[e]) ----------------
// 128x128 tile, BK=64. A-operand double-buffered (T4-lite): A(k+1) issued each
// iter and kept in flight across raw s_barrier via counted vmcnt(4); B drained
// each iter (warm operand). LDS 48 KB -> 3 blocks/CU; (256,3) caps regs.
__global__ __launch_bounds__(256, 3) void gemm1_kernel(const unsigned short* __restrict__ xb,
                                                    const unsigned short* __restrict__ wfcb,
                                                    const float* __restrict__ bfc,
                                                    const int* __restrict__ pair_token,
                                                    const int* __restrict__ tile2e,
                                                    int chunk_base,
                                                    unsigned short* __restrict__ h) {
    int tile = chunk_base + blockIdx.y;
    int e = tile2e[tile];
    if (e < 0) return;
    int ftile = blockIdx.x;                      // 0..31

    __shared__ unsigned short sA[2][128 * 64];   // 2 x 16 KB
    __shared__ unsigned short sB[128 * 64];      // 16 KB   (total 48 KB)

    int tid = threadIdx.x;
    int wave = tid >> 6, lane = tid & 63;
    int lrow = lane >> 3;                        // 0..7
    int kblk = (lane & 7) ^ lrow;                // swizzled source k-block

    const unsigned short* wB = wfcb + (size_t)e * FDIM * DDIM + (size_t)ftile * 128 * DDIM;
    const unsigned short* aBase[4];
    const unsigned short* bBase[4];
#pragma unroll
    for (int t = 0; t < 4; t++) {
        int row = wave * 32 + t * 8 + lrow;
        aBase[t] = xb + (size_t)pair_token[tile * 128 + row] * DDIM + kblk * 8;
        bBase[t] = wB + (size_t)row * DDIM + kblk * 8;
    }

    f32x4 zero = {0.f, 0.f, 0.f, 0.f};
    f32x4 acc[4][4];
#pragma unroll
    for (int i = 0; i < 4; i++)
#pragma unroll
        for (int j = 0; j < 4; j++) acc[i][j] = zero;

    int wm = (wave >> 1) * 64, wn = (wave & 1) * 64;
    int quad = lane >> 4, l16 = lane & 15;
    int r7 = l16 & 7;

    constexpr int NK = DDIM / 64;                // 16
    // prologue: A(0) -> sA[0]
#pragma unroll
    for (int t = 0; t < 4; t++) {
        gload16(aBase[t], &sA[0][(wave * 32 + t * 8) * 64]);
        aBase[t] += 64;
    }
    SCHED0();

#pragma unroll 1
    for (int k = 0; k < NK - 1; ++k) {
#pragma unroll
        for (int t = 0; t < 4; t++) {            // B(k)
            gload16(bBase[t], &sB[(wave * 32 + t * 8) * 64]);
            bBase[t] += 64;
        }
        const unsigned short* sAn = sA[(k + 1) & 1];
#pragma unroll
        for (int t = 0; t < 4; t++) {            // A(k+1)
            gload16(aBase[t], &sAn[(wave * 32 + t * 8) * 64]);
            aBase[t] += 64;
        }
        SCHED0();
        asm volatile("s_waitcnt vmcnt(4)" ::: "memory");   // A(k),B(k) landed; A(k+1) in flight
        SCHED0();
        __builtin_amdgcn_s_barrier();
        SCHED0();
        const unsigned short* sAc = sA[k & 1];
#pragma unroll
        for (int ks = 0; ks < 64; ks += 32) {
            int g = (ks >> 3) + quad;            // global k-block 0..7
            bf16x8 af[4], bfr[4];
#pragma unroll
            for (int i = 0; i < 4; i++) {
                int row = wm + i * 16 + l16;
                af[i] = *(const bf16x8*)&sAc[row * 64 + ((g ^ r7) << 3)];
            }
#pragma unroll
            for (int j = 0; j < 4; j++) {
                int row = wn + j * 16 + l16;
                bfr[j] = *(const bf16x8*)&sB[row * 64 + ((g ^ r7) << 3)];
            }
#pragma unroll
            for (int i = 0; i < 4; i++)
#pragma unroll
                for (int j = 0; j < 4; j++)
                    acc[i][j] = __builtin_amdgcn_mfma_f32_16x16x32_bf16(af[i], bfr[j], acc[i][j], 0, 0, 0);
        }
        SCHED0();
        __builtin_amdgcn_s_barrier();
        SCHED0();
    }
    // final iter: B(NK-1), full drain
    {
#pragma unroll
        for (int t = 0; t < 4; t++)
            gload16(bBase[t], &sB[(wave * 32 + t * 8) * 64]);
        SCHED0();
        asm volatile("s_waitcnt vmcnt(0)" ::: "memory");
        SCHED0();
        __builtin_amdgcn_s_barrier();
        SCHED0();
        const unsigned short* sAc = sA[(NK - 1) & 1];
#pragma unroll
        for (int ks = 0; ks < 64; ks += 32) {
            int g = (ks >> 3) + quad;
            bf16x8 af[4], bfr[4];
#pragma unroll
            for (int i = 0; i < 4; i++) {
                int row = wm + i * 16 + l16;
                af[i] = *(const bf16x8*)&sAc[row * 64 + ((g ^ r7) << 3)];
            }
#pragma unroll
            for (int j = 0; j < 4; j++) {
                int row = wn + j * 16 + l16;
                bfr[j] = *(const bf16x8*)&sB[row * 64 + ((g ^ r7) << 3)];
            }
#pragma unroll
            for (int i = 0; i < 4; i++)
#pragma unroll
                for (int j = 0; j < 4; j++)
                    acc[i][j] = __builtin_amdgcn_mfma_f32_16x16x32_bf16(af[i], bfr[j], acc[i][j], 0, 0, 0);
        }
    }

    // epilogue: bias + exact gelu -> bf16 h (chunk-local rows)
    unsigned short* hrow_base = h + (size_t)blockIdx.y * 128 * FDIM;
#pragma unroll
    for (int i = 0; i < 4; i++) {
#pragma unroll
        for (int j = 0; j < 4; j++) {
            int col = wn + j * 16 + l16;
            int f = ftile * 128 + col;
            float bias = bfc[e * FDIM + f];
#pragma unroll
            for (int r = 0; r < 4; r++) {
                int row = wm + i * 16 + quad * 4 + r;
                float v = acc[i][j][r] + bias;
                v = 0.5f * v * (1.f + erff(v * 0.70710678118654752f));
                hrow_base[(size_t)row * FDIM + f] = f2bf(v);
            }
        }
    }
}

// ---------------- GEMM2: out[token] += (h @ wproj[e]^T + bproj[e]) * gate ----------------
// Same A-dbuf counted-vmcnt pipeline; A here is the HBM-cold h stream.
__global__ __launch_bounds__(256, 3) void gemm2_kernel(const unsigned short* __restrict__ h,
                                                    const unsigned short* __restrict__ wprojb,
                                                    const float* __restrict__ bproj,
                                                    const int* __restrict__ pair_token,
                                                    const float* __restrict__ pair_gate,
                                                    const int* __restrict__ tile2e,
                                                    int chunk_base,
                                                    float* __restrict__ out) {
    int tile = chunk_base + blockIdx.y;
    int e = tile2e[tile];
    if (e < 0) return;
    int dtile = blockIdx.x;                      // 0..7

    __shared__ unsigned short sA[2][128 * 64];
    __shared__ unsigned short sB[128 * 64];      // total 48 KB

    int tid = threadIdx.x;
    int wave = tid >> 6, lane = tid & 63;
    int lrow = lane >> 3;
    int kblk = (lane & 7) ^ lrow;

    const unsigned short* hA = h + (size_t)blockIdx.y * 128 * FDIM;
    const unsigned short* wB = wprojb + (size_t)e * DDIM * FDIM + (size_t)dtile * 128 * FDIM;
    const unsigned short* aBase[4];
    const unsigned short* bBase[4];
#pragma unroll
    for (int t = 0; t < 4; t++) {
        int row = wave * 32 + t * 8 + lrow;
        aBase[t] = hA + (size_t)row * FDIM + kblk * 8;
        bBase[t] = wB + (size_t)row * FDIM + kblk * 8;
    }

    f32x4 zero = {0.f, 0.f, 0.f, 0.f};
    f32x4 acc[4][4];
#pragma unroll
    for (int i = 0; i < 4; i++)
#pragma unroll
        for (int j = 0; j < 4; j++) acc[i][j] = zero;

    int wm = (wave >> 1) * 64, wn = (wave & 1) * 64;
    int quad = lane >> 4, l16 = lane & 15;
    int r7 = l16 & 7;

    constexpr int NK = FDIM / 64;                // 64
    // prologue: A(0) -> sA[0]
#pragma unroll
    for (int t = 0; t < 4; t++) {
        gload16(aBase[t], &sA[0][(wave * 32 + t * 8) * 64]);
        aBase[t] += 64;
    }
    SCHED0();

#pragma unroll 1
    for (int k = 0; k < NK - 1; ++k) {
#pragma unroll
        for (int t = 0; t < 4; t++) {            // B(k)
            gload16(bBase[t], &sB[(wave * 32 + t * 8) * 64]);
            bBase[t] += 64;
        }
        const unsigned short* sAn = sA[(k + 1) & 1];
#pragma unroll
        for (int t = 0; t < 4; t++) {            // A(k+1)
            gload16(aBase[t], &sAn[(wave * 32 + t * 8) * 64]);
            aBase[t] += 64;
        }
        SCHED0();
        asm volatile("s_waitcnt vmcnt(4)" ::: "memory");
        SCHED0();
        __builtin_amdgcn_s_barrier();
        SCHED0();
        const unsigned short* sAc = sA[k & 1];
#pragma unroll
        for (int ks = 0; ks < 64; ks += 32) {
            int g = (ks >> 3) + quad;
            bf16x8 af[4], bfr[4];
#pragma unroll
            for (int i = 0; i < 4; i++) {
                int row = wm + i * 16 + l16;
                af[i] = *(const bf16x8*)&sAc[row * 64 + ((g ^ r7) << 3)];
            }
#pragma unroll
            for (int j = 0; j < 4; j++) {
                int row = wn + j * 16 + l16;
                bfr[j] = *(const bf16x8*)&sB[row * 64 + ((g ^ r7) << 3)];
            }
#pragma unroll
            for (int i = 0; i < 4; i++)
#pragma unroll
                for (int j = 0; j < 4; j++)
                    acc[i][j] = __builtin_amdgcn_mfma_f32_16x16x32_bf16(af[i], bfr[j], acc[i][j], 0, 0, 0);
        }
        SCHED0();
        __builtin_amdgcn_s_barrier();
        SCHED0();
    }
    {
#pragma unroll
        for (int t = 0; t < 4; t++)
            gload16(bBase[t], &sB[(wave * 32 + t * 8) * 64]);
        SCHED0();
        asm volatile("s_waitcnt vmcnt(0)" ::: "memory");
        SCHED0();
        __builtin_amdgcn_s_barrier();
        SCHED0();
        const unsigned short* sAc = sA[(NK - 1) & 1];
#pragma unroll
        for (int ks = 0; ks < 64; ks += 32) {
            int g = (ks >> 3) + quad;
            bf16x8 af[4], bfr[4];
#pragma unroll
            for (int i = 0; i < 4; i++) {
                int row = wm + i * 16 + l16;
                af[i] = *(const bf16x8*)&sAc[row * 64 + ((g ^ r7) << 3)];
            }
#pragma unroll
            for (int j = 0; j < 4; j++) {
                int row = wn + j * 16 + l16;
                bfr[j] = *(const bf16x8*)&sB[row * 64 + ((g ^ r7) << 3)];
            }
#pragma unroll
            for (int i = 0; i < 4; i++)
#pragma unroll
                for (int j = 0; j < 4; j++)
                    acc[i][j] = __builtin_amdgcn_mfma_f32_16x16x32_bf16(af[i], bfr[j], acc[i][j], 0, 0, 0);
        }
    }

    // epilogue: bias, gate, atomic scatter-add into out (exactly 2 adds/element)
#pragma unroll
    for (int i = 0; i < 4; i++) {
#pragma unroll
        for (int j = 0; j < 4; j++) {
            int col = wn + j * 16 + l16;
            int d = dtile * 128 + col;
            float bias = bproj[e * DDIM + d];
#pragma unroll
            for (int r = 0; r < 4; r++) {
                int row = wm + i * 16 + quad * 4 + r;
                int tok = pair_token[tile * 128 + row];     // L1-cached
                float gate = pair_gate[tile * 128 + row];
                float v = (acc[i][j][r] + bias) * gate;
                atomicAdd(&out[(size_t)tok * DDIM + d], v);
            }
        }
    }
}

// ---------------- LayerNorm (in-place on out) ----------------
__global__ __launch_bounds__(256) void ln_kernel(float* __restrict__ out,
                                                 const float* __restrict__ g,
                                                 const float* __restrict__ b) {
    __shared__ float s1[4], s2[4];
    int t = blockIdx.x, tid = threadIdx.x;
    float* row = out + (size_t)t * DDIM;
    float4 v = ((const float4*)row)[tid];
    float sum = v.x + v.y + v.z + v.w;
    float sq = v.x * v.x + v.y * v.y + v.z * v.z + v.w * v.w;
#pragma unroll
    for (int off = 32; off > 0; off >>= 1) {
        sum += __shfl_down(sum, off);
        sq  += __shfl_down(sq, off);
    }
    int wave = tid >> 6, lane = tid & 63;
    if (lane == 0) { s1[wave] = sum; s2[wave] = sq; }
    __syncthreads();
    float tot = s1[0] + s1[1] + s1[2] + s1[3];
    float totsq = s2[0] + s2[1] + s2[2] + s2[3];
    float mu = tot * (1.f / DDIM);
    float var = totsq * (1.f / DDIM) - mu * mu;
    float rs = rsqrtf(var + 1e-5f);
    float4 gv = ((const float4*)g)[tid];
    float4 bv = ((const float4*)b)[tid];
    float4 o;
    o.x = (v.x - mu) * rs * gv.x + bv.x;
    o.y = (v.y - mu) * rs * gv.y + bv.y;
    o.z = (v.z - mu) * rs * gv.z + bv.z;
    o.w = (v.w - mu) * rs * gv.w + bv.w;
    ((float4*)row)[tid] = o;
}

extern "C" void kernel_launch(void* const* d_in, const int* in_sizes, int n_in,
                              void* d_out, int out_size, void* d_ws, size_t ws_size,
                              hipStream_t stream) {
    const float* x   = (const float*)d_in[0];
    const float* rw  = (const float*)d_in[1];
    const float* wfc = (const float*)d_in[2];
    const float* bfc = (const float*)d_in[3];
    const float* wpr = (const float*)d_in[4];
    const float* bpr = (const float*)d_in[5];
    const float* lng = (const float*)d_in[6];
    const float* lnb = (const float*)d_in[7];

    float* out = (float*)d_out;                       // [16384,1024]
    float* logits = out + (size_t)NTOK * DDIM;        // [16384,8]

    char* ws = (char*)d_ws;
    unsigned short* xb     = (unsigned short*)(ws + WS_XB);
    unsigned short* wfcb   = (unsigned short*)(ws + WS_WFCB);
    unsigned short* wprojb = (unsigned short*)(ws + WS_WPROJB);
    unsigned short* hbuf   = (unsigned short*)(ws + WS_H);

    // Pick the largest chunk size (h tiles) that fits in ws. ws_size is fixed
    // across calls, so this branch is graph-capture safe.
    size_t aux_bytes = (size_t)PADPAIRS * 8 + (size_t)NTOK * 16 + 8192;
    int ct = 66;                                      // fallback (4 chunks, known-fit)
    if (ws_size >= WS_H + (size_t)264 * 128 * FDIM * 2 + aux_bytes)      ct = 264;
    else if (ws_size >= WS_H + (size_t)132 * 128 * FDIM * 2 + aux_bytes) ct = 132;
    int nchunks = MAXTILES / ct;

    char* aux = ws + WS_H + (size_t)ct * 128 * FDIM * 2;
    int*   ptok  = (int*)aux;
    float* pgate = (float*)(aux + (size_t)PADPAIRS * 4);
    int*   tidx  = (int*)(aux + (size_t)PADPAIRS * 8);
    float* tgate = (float*)(aux + (size_t)PADPAIRS * 8 + (size_t)NTOK * 8);
    int*   meta  = (int*)(aux + (size_t)PADPAIRS * 8 + (size_t)NTOK * 16);
    // meta layout (ints): counts[0..127] stride16, cursor[128..255] stride16,
    // segs[256..263], total[264], tile2e[272..]
    int* counts = meta;           // padded, counts[e*16]
    int* cursor = meta + 128;     // padded, cursor[e*16]
    int* segs   = meta + 256;     // 8
    int* total  = meta + 264;     // 1
    int* tile2e = meta + 272;     // 264

    hipMemsetAsync(out, 0, (size_t)NTOK * DDIM * sizeof(float), stream);
    hipMemsetAsync(meta, 0, 2048, stream);

    convert_kernel<<<(NEXP * FDIM * DDIM) / 4 / 256, 256, 0, stream>>>(wfc, wfcb);
    convert_kernel<<<(NEXP * DDIM * FDIM) / 4 / 256, 256, 0, stream>>>(wpr, wprojb);
    router_kernel<<<NTOK / 16, 256, 0, stream>>>(x, rw, xb, logits, tidx, tgate, counts);
    seg_plan<<<1, 256, 0, stream>>>(counts, segs, tile2e, total, ptok, pgate);
    scatter_k<<<NTOK / 256, 256, 0, stream>>>(tidx, tgate, segs, cursor, ptok, pgate);

    for (int c = 0; c < nchunks; c++) {
        gemm1_kernel<<<dim3(FDIM / 128, ct), 256, 0, stream>>>(
            xb, wfcb, bfc, ptok, tile2e, c * ct, hbuf);
        gemm2_kernel<<<dim3(DDIM / 128, ct), 256, 0, stream>>>(
            hbuf, wprojb, bpr, ptok, pgate, tile2e, c * ct, out);
    }
    ln_kernel<<<NTOK, 256, 0, stream>>>(out, lng, lnb);
}

// Round 5
// 1121.858 us; speedup vs baseline: 1.3960x; 1.0383x over previous
//
#include <hip/hip_runtime.h>

// Problem constants (B=8, T=2048 -> NTOK=16384; D=1024, E=8, F=4096, top_k=2)
#define NTOK 16384
#define DDIM 1024
#define FDIM 4096
#define NEXP 8
#define PADPAIRS 33792          // 264 * 128 (worst-case 128-padded segments)
#define MAXTILES 264
#define TILE2E_PAD 280          // padded so partial last chunks read -1, not garbage

// Fixed workspace layout (bytes); h + aux are placed dynamically after these.
#define WS_XB      0ull                    // bf16 x       [NTOK][D]      33,554,432
#define WS_WFCB    33554432ull             // bf16 wfc     [E][F][D]      67,108,864
#define WS_WPROJB  100663296ull            // bf16 wproj   [E][D][F]      67,108,864
#define WS_H       167772160ull            // bf16 h       [ct*128][F]    (dynamic)

typedef short bf16x8 __attribute__((ext_vector_type(8)));
typedef float f32x4 __attribute__((ext_vector_type(4)));

__device__ __forceinline__ unsigned short f2bf(float f) {
    unsigned int u = __float_as_uint(f);
    u += 0x7fffu + ((u >> 16) & 1u);   // round to nearest even
    return (unsigned short)(u >> 16);
}

// CK-style async global->LDS direct load, 16B per lane.
// LDS dest = wave-uniform base + lane*16; global addr is per-lane.
__device__ __forceinline__ void gload16(const unsigned short* g, const unsigned short* lds) {
    __builtin_amdgcn_global_load_lds(
        (const __attribute__((address_space(1))) unsigned int*)(unsigned long long)(const void*)g,
        (__attribute__((address_space(3))) unsigned int*)(unsigned int)(unsigned long long)(const void*)lds,
        16, 0, 0);
}

#define SCHED0() __builtin_amdgcn_sched_barrier(0)

// ---------------- fp32 -> bf16 weight conversion ----------------
__global__ __launch_bounds__(256) void convert_kernel(const float* __restrict__ src,
                                                      unsigned short* __restrict__ dst) {
    int i = blockIdx.x * 256 + threadIdx.x;     // one float4 per thread
    float4 v = ((const float4*)src)[i];
    ushort4 o;
    o.x = f2bf(v.x); o.y = f2bf(v.y); o.z = f2bf(v.z); o.w = f2bf(v.w);
    ((ushort4*)dst)[i] = o;
}

// ---------------- router: logits (fp32), top-2 + softmax gates, x->bf16 ----------------
// counts is padded: counts[e*16] (64 B apart) to avoid hot-cacheline atomics.
__global__ __launch_bounds__(256) void router_kernel(const float* __restrict__ x,
                                                     const float* __restrict__ rw,
                                                     unsigned short* __restrict__ xb,
                                                     float* __restrict__ logits,
                                                     int* __restrict__ tok_idx,
                                                     float* __restrict__ tok_gate,
                                                     int* __restrict__ counts) {
    __shared__ float srw[NEXP * DDIM];          // 32 KiB
    __shared__ int scnt[NEXP];
    int tid = threadIdx.x;
    if (tid < NEXP) scnt[tid] = 0;
    for (int i = tid; i < NEXP * DDIM / 4; i += 256)
        ((float4*)srw)[i] = ((const float4*)rw)[i];
    __syncthreads();

    int wave = tid >> 6, lane = tid & 63;
    const float4* srw4 = (const float4*)srw;

    for (int j = 0; j < 4; j++) {
        int t = blockIdx.x * 16 + wave * 4 + j;
        const float4* xr = (const float4*)(x + (size_t)t * DDIM);
        ushort4* xbr = (ushort4*)(xb + (size_t)t * DDIM);

        float acc[NEXP];
#pragma unroll
        for (int e = 0; e < NEXP; e++) acc[e] = 0.f;

#pragma unroll
        for (int i = 0; i < 4; i++) {
            int k4 = i * 64 + lane;
            float4 xv = xr[k4];
            ushort4 o;
            o.x = f2bf(xv.x); o.y = f2bf(xv.y); o.z = f2bf(xv.z); o.w = f2bf(xv.w);
            xbr[k4] = o;
#pragma unroll
            for (int e = 0; e < NEXP; e++) {
                float4 wv = srw4[e * 256 + k4];
                acc[e] += xv.x * wv.x + xv.y * wv.y + xv.z * wv.z + xv.w * wv.w;
            }
        }
#pragma unroll
        for (int off = 1; off < 64; off <<= 1) {
#pragma unroll
            for (int e = 0; e < NEXP; e++) acc[e] += __shfl_xor(acc[e], off);
        }
        if (lane == 0) {
            float v0 = -1e30f, v1 = -1e30f; int i0 = 0, i1 = 0;
#pragma unroll
            for (int e = 0; e < NEXP; e++) {
                float v = acc[e];
                logits[(size_t)t * NEXP + e] = v;
                if (v > v0)      { v1 = v0; i1 = i0; v0 = v; i0 = e; }
                else if (v > v1) { v1 = v;  i1 = e; }
            }
            float d = __expf(v1 - v0);              // <= 1, stable
            float g0 = 1.f / (1.f + d);
            float g1 = d * g0;
            tok_idx[t * 2 + 0] = i0; tok_idx[t * 2 + 1] = i1;
            tok_gate[t * 2 + 0] = g0; tok_gate[t * 2 + 1] = g1;
            atomicAdd(&scnt[i0], 1);
            atomicAdd(&scnt[i1], 1);
        }
    }
    __syncthreads();
    if (tid < NEXP) atomicAdd(&counts[tid * 16], scnt[tid]);
}

// ---------------- segment planning + pair-array padding init ----------------
__global__ void seg_plan(const int* __restrict__ counts, int* __restrict__ seg_start,
                         int* __restrict__ tile2e, int* __restrict__ total_tiles,
                         int* __restrict__ pair_token, float* __restrict__ pair_gate) {
    if (threadIdx.x == 0) {
        int cum = 0, tl = 0;
        for (int e = 0; e < NEXP; e++) {
            seg_start[e] = cum;
            int tiles = (counts[e * 16] + 127) >> 7;
            for (int i = 0; i < tiles; i++) tile2e[tl++] = e;
            cum += tiles << 7;
        }
        for (int i = tl; i < TILE2E_PAD; i++) tile2e[i] = -1;
        *total_tiles = tl;
    }
    for (int i = threadIdx.x; i < PADPAIRS; i += 256) {
        pair_token[i] = 0;
        pair_gate[i] = 0.f;
    }
}

// ---------------- scatter tokens into per-expert segments ----------------
// Block-aggregated: LDS ranks + 8 padded global atomics per block (vs 512
// same-cacheline device atomics).
__global__ __launch_bounds__(256) void scatter_k(const int* __restrict__ tok_idx,
                                                 const float* __restrict__ tok_gate,
                                                 const int* __restrict__ seg_start,
                                                 int* __restrict__ cursor,
                                                 int* __restrict__ pair_token,
                                                 float* __restrict__ pair_gate) {
    __shared__ int lcnt[NEXP];
    __shared__ int lbase[NEXP];
    int tid = threadIdx.x;
    if (tid < NEXP) lcnt[tid] = 0;
    __syncthreads();
    int t = blockIdx.x * 256 + tid;
    int e0 = tok_idx[t * 2 + 0], e1 = tok_idx[t * 2 + 1];
    float g0 = tok_gate[t * 2 + 0], g1 = tok_gate[t * 2 + 1];
    int r0 = atomicAdd(&lcnt[e0], 1);
    int r1 = atomicAdd(&lcnt[e1], 1);
    __syncthreads();
    if (tid < NEXP) lbase[tid] = atomicAdd(&cursor[tid * 16], lcnt[tid]);
    __syncthreads();
    int p0 = seg_start[e0] + lbase[e0] + r0;
    int p1 = seg_start[e1] + lbase[e1] + r1;
    pair_token[p0] = t; pair_gate[p0] = g0;
    pair_token[p1] = t; pair_gate[p1] = g1;
}

// ---------------- GEMM1: h = gelu(x_gathered @ wfc[e]^T + bfc[e]) ----------------
// 128x128 tile, BK=64. A-operand double-buffered (T4-lite): A(k+1) issued each
// iter and kept in flight across raw s_barrier via counted vmcnt(4); B drained
// each iter (warm operand). LDS 48 KB -> 3 blocks/CU; (256,3) caps regs.
__global__ __launch_bounds__(256, 3) void gemm1_kernel(const unsigned short* __restrict__ xb,
                                                    const unsigned short* __restrict__ wfcb,
                                                    const float* __restrict__ bfc,
                                                    const int* __restrict__ pair_token,
                                                    const int* __restrict__ tile2e,
                                                    int chunk_base,
                                                    unsigned short* __restrict__ h) {
    int tile = chunk_base + blockIdx.y;
    int e = tile2e[tile];
    if (e < 0) return;
    int ftile = blockIdx.x;                      // 0..31

    __shared__ unsigned short sA[2][128 * 64];   // 2 x 16 KB
    __shared__ unsigned short sB[128 * 64];      // 16 KB   (total 48 KB)

    int tid = threadIdx.x;
    int wave = tid >> 6, lane = tid & 63;
    int lrow = lane >> 3;                        // 0..7
    int kblk = (lane & 7) ^ lrow;                // swizzled source k-block

    const unsigned short* wB = wfcb + (size_t)e * FDIM * DDIM + (size_t)ftile * 128 * DDIM;
    const unsigned short* aBase[4];
    const unsigned short* bBase[4];
#pragma unroll
    for (int t = 0; t < 4; t++) {
        int row = wave * 32 + t * 8 + lrow;
        aBase[t] = xb + (size_t)pair_token[tile * 128 + row] * DDIM + kblk * 8;
        bBase[t] = wB + (size_t)row * DDIM + kblk * 8;
    }

    f32x4 zero = {0.f, 0.f, 0.f, 0.f};
    f32x4 acc[4][4];
#pragma unroll
    for (int i = 0; i < 4; i++)
#pragma unroll
        for (int j = 0; j < 4; j++) acc[i][j] = zero;

    int wm = (wave >> 1) * 64, wn = (wave & 1) * 64;
    int quad = lane >> 4, l16 = lane & 15;
    int r7 = l16 & 7;

    constexpr int NK = DDIM / 64;                // 16
    // prologue: A(0) -> sA[0]
#pragma unroll
    for (int t = 0; t < 4; t++) {
        gload16(aBase[t], &sA[0][(wave * 32 + t * 8) * 64]);
        aBase[t] += 64;
    }
    SCHED0();

#pragma unroll 1
    for (int k = 0; k < NK - 1; ++k) {
#pragma unroll
        for (int t = 0; t < 4; t++) {            // B(k)
            gload16(bBase[t], &sB[(wave * 32 + t * 8) * 64]);
            bBase[t] += 64;
        }
        const unsigned short* sAn = sA[(k + 1) & 1];
#pragma unroll
        for (int t = 0; t < 4; t++) {            // A(k+1)
            gload16(aBase[t], &sAn[(wave * 32 + t * 8) * 64]);
            aBase[t] += 64;
        }
        SCHED0();
        asm volatile("s_waitcnt vmcnt(4)" ::: "memory");   // A(k),B(k) landed; A(k+1) in flight
        SCHED0();
        __builtin_amdgcn_s_barrier();
        SCHED0();
        const unsigned short* sAc = sA[k & 1];
#pragma unroll
        for (int ks = 0; ks < 64; ks += 32) {
            int g = (ks >> 3) + quad;            // global k-block 0..7
            bf16x8 af[4], bfr[4];
#pragma unroll
            for (int i = 0; i < 4; i++) {
                int row = wm + i * 16 + l16;
                af[i] = *(const bf16x8*)&sAc[row * 64 + ((g ^ r7) << 3)];
            }
#pragma unroll
            for (int j = 0; j < 4; j++) {
                int row = wn + j * 16 + l16;
                bfr[j] = *(const bf16x8*)&sB[row * 64 + ((g ^ r7) << 3)];
            }
#pragma unroll
            for (int i = 0; i < 4; i++)
#pragma unroll
                for (int j = 0; j < 4; j++)
                    acc[i][j] = __builtin_amdgcn_mfma_f32_16x16x32_bf16(af[i], bfr[j], acc[i][j], 0, 0, 0);
        }
        SCHED0();
        __builtin_amdgcn_s_barrier();
        SCHED0();
    }
    // final iter: B(NK-1), full drain
    {
#pragma unroll
        for (int t = 0; t < 4; t++)
            gload16(bBase[t], &sB[(wave * 32 + t * 8) * 64]);
        SCHED0();
        asm volatile("s_waitcnt vmcnt(0)" ::: "memory");
        SCHED0();
        __builtin_amdgcn_s_barrier();
        SCHED0();
        const unsigned short* sAc = sA[(NK - 1) & 1];
#pragma unroll
        for (int ks = 0; ks < 64; ks += 32) {
            int g = (ks >> 3) + quad;
            bf16x8 af[4], bfr[4];
#pragma unroll
            for (int i = 0; i < 4; i++) {
                int row = wm + i * 16 + l16;
                af[i] = *(const bf16x8*)&sAc[row * 64 + ((g ^ r7) << 3)];
            }
#pragma unroll
            for (int j = 0; j < 4; j++) {
                int row = wn + j * 16 + l16;
                bfr[j] = *(const bf16x8*)&sB[row * 64 + ((g ^ r7) << 3)];
            }
#pragma unroll
            for (int i = 0; i < 4; i++)
#pragma unroll
                for (int j = 0; j < 4; j++)
                    acc[i][j] = __builtin_amdgcn_mfma_f32_16x16x32_bf16(af[i], bfr[j], acc[i][j], 0, 0, 0);
        }
    }

    // epilogue: bias + exact gelu -> bf16 h (chunk-local rows)
    unsigned short* hrow_base = h + (size_t)blockIdx.y * 128 * FDIM;
#pragma unroll
    for (int i = 0; i < 4; i++) {
#pragma unroll
        for (int j = 0; j < 4; j++) {
            int col = wn + j * 16 + l16;
            int f = ftile * 128 + col;
            float bias = bfc[e * FDIM + f];
#pragma unroll
            for (int r = 0; r < 4; r++) {
                int row = wm + i * 16 + quad * 4 + r;
                float v = acc[i][j][r] + bias;
                v = 0.5f * v * (1.f + erff(v * 0.70710678118654752f));
                hrow_base[(size_t)row * FDIM + f] = f2bf(v);
            }
        }
    }
}

// ---------------- GEMM2: out[token] += (h @ wproj[e]^T + bproj[e]) * gate ----------------
// Same A-dbuf counted-vmcnt pipeline; A here is the HBM-cold h stream.
// XCD-grouped remap (T1): the 8 dtile-siblings of a tile are consecutive slots
// on ONE XCD (assumes id%8 round-robin), so the 1 MB h-panel is fetched once
// into that XCD's L2 and hit 7x. Bijective because ct % 8 == 0.
__global__ __launch_bounds__(256, 3) void gemm2_kernel(const unsigned short* __restrict__ h,
                                                    const unsigned short* __restrict__ wprojb,
                                                    const float* __restrict__ bproj,
                                                    const int* __restrict__ pair_token,
                                                    const float* __restrict__ pair_gate,
                                                    const int* __restrict__ tile2e,
                                                    int chunk_base,
                                                    float* __restrict__ out) {
    int flat = blockIdx.x + (blockIdx.y << 3);   // grid dim3(8, ct)
    int xcd  = flat & 7;
    int slot = flat >> 3;
    int tl   = ((slot >> 3) << 3) + xcd;         // chunk-local tile
    int dtile = slot & 7;                        // 0..7

    int tile = chunk_base + tl;
    int e = tile2e[tile];
    if (e < 0) return;

    __shared__ unsigned short sA[2][128 * 64];
    __shared__ unsigned short sB[128 * 64];      // total 48 KB

    int tid = threadIdx.x;
    int wave = tid >> 6, lane = tid & 63;
    int lrow = lane >> 3;
    int kblk = (lane & 7) ^ lrow;

    const unsigned short* hA = h + (size_t)tl * 128 * FDIM;
    const unsigned short* wB = wprojb + (size_t)e * DDIM * FDIM + (size_t)dtile * 128 * FDIM;
    const unsigned short* aBase[4];
    const unsigned short* bBase[4];
#pragma unroll
    for (int t = 0; t < 4; t++) {
        int row = wave * 32 + t * 8 + lrow;
        aBase[t] = hA + (size_t)row * FDIM + kblk * 8;
        bBase[t] = wB + (size_t)row * FDIM + kblk * 8;
    }

    f32x4 zero = {0.f, 0.f, 0.f, 0.f};
    f32x4 acc[4][4];
#pragma unroll
    for (int i = 0; i < 4; i++)
#pragma unroll
        for (int j = 0; j < 4; j++) acc[i][j] = zero;

    int wm = (wave >> 1) * 64, wn = (wave & 1) * 64;
    int quad = lane >> 4, l16 = lane & 15;
    int r7 = l16 & 7;

    constexpr int NK = FDIM / 64;                // 64
    // prologue: A(0) -> sA[0]
#pragma unroll
    for (int t = 0; t < 4; t++) {
        gload16(aBase[t], &sA[0][(wave * 32 + t * 8) * 64]);
        aBase[t] += 64;
    }
    SCHED0();

#pragma unroll 1
    for (int k = 0; k < NK - 1; ++k) {
#pragma unroll
        for (int t = 0; t < 4; t++) {            // B(k)
            gload16(bBase[t], &sB[(wave * 32 + t * 8) * 64]);
            bBase[t] += 64;
        }
        const unsigned short* sAn = sA[(k + 1) & 1];
#pragma unroll
        for (int t = 0; t < 4; t++) {            // A(k+1)
            gload16(aBase[t], &sAn[(wave * 32 + t * 8) * 64]);
            aBase[t] += 64;
        }
        SCHED0();
        asm volatile("s_waitcnt vmcnt(4)" ::: "memory");
        SCHED0();
        __builtin_amdgcn_s_barrier();
        SCHED0();
        const unsigned short* sAc = sA[k & 1];
#pragma unroll
        for (int ks = 0; ks < 64; ks += 32) {
            int g = (ks >> 3) + quad;
            bf16x8 af[4], bfr[4];
#pragma unroll
            for (int i = 0; i < 4; i++) {
                int row = wm + i * 16 + l16;
                af[i] = *(const bf16x8*)&sAc[row * 64 + ((g ^ r7) << 3)];
            }
#pragma unroll
            for (int j = 0; j < 4; j++) {
                int row = wn + j * 16 + l16;
                bfr[j] = *(const bf16x8*)&sB[row * 64 + ((g ^ r7) << 3)];
            }
#pragma unroll
            for (int i = 0; i < 4; i++)
#pragma unroll
                for (int j = 0; j < 4; j++)
                    acc[i][j] = __builtin_amdgcn_mfma_f32_16x16x32_bf16(af[i], bfr[j], acc[i][j], 0, 0, 0);
        }
        SCHED0();
        __builtin_amdgcn_s_barrier();
        SCHED0();
    }
    {
#pragma unroll
        for (int t = 0; t < 4; t++)
            gload16(bBase[t], &sB[(wave * 32 + t * 8) * 64]);
        SCHED0();
        asm volatile("s_waitcnt vmcnt(0)" ::: "memory");
        SCHED0();
        __builtin_amdgcn_s_barrier();
        SCHED0();
        const unsigned short* sAc = sA[(NK - 1) & 1];
#pragma unroll
        for (int ks = 0; ks < 64; ks += 32) {
            int g = (ks >> 3) + quad;
            bf16x8 af[4], bfr[4];
#pragma unroll
            for (int i = 0; i < 4; i++) {
                int row = wm + i * 16 + l16;
                af[i] = *(const bf16x8*)&sAc[row * 64 + ((g ^ r7) << 3)];
            }
#pragma unroll
            for (int j = 0; j < 4; j++) {
                int row = wn + j * 16 + l16;
                bfr[j] = *(const bf16x8*)&sB[row * 64 + ((g ^ r7) << 3)];
            }
#pragma unroll
            for (int i = 0; i < 4; i++)
#pragma unroll
                for (int j = 0; j < 4; j++)
                    acc[i][j] = __builtin_amdgcn_mfma_f32_16x16x32_bf16(af[i], bfr[j], acc[i][j], 0, 0, 0);
        }
    }

    // epilogue: bias, gate, atomic scatter-add into out (exactly 2 adds/element)
#pragma unroll
    for (int i = 0; i < 4; i++) {
#pragma unroll
        for (int j = 0; j < 4; j++) {
            int col = wn + j * 16 + l16;
            int d = dtile * 128 + col;
            float bias = bproj[e * DDIM + d];
#pragma unroll
            for (int r = 0; r < 4; r++) {
                int row = wm + i * 16 + quad * 4 + r;
                int tok = pair_token[tile * 128 + row];     // L1-cached
                float gate = pair_gate[tile * 128 + row];
                float v = (acc[i][j][r] + bias) * gate;
                atomicAdd(&out[(size_t)tok * DDIM + d], v);
            }
        }
    }
}

// ---------------- LayerNorm (in-place on out) ----------------
__global__ __launch_bounds__(256) void ln_kernel(float* __restrict__ out,
                                                 const float* __restrict__ g,
                                                 const float* __restrict__ b) {
    __shared__ float s1[4], s2[4];
    int t = blockIdx.x, tid = threadIdx.x;
    float* row = out + (size_t)t * DDIM;
    float4 v = ((const float4*)row)[tid];
    float sum = v.x + v.y + v.z + v.w;
    float sq = v.x * v.x + v.y * v.y + v.z * v.z + v.w * v.w;
#pragma unroll
    for (int off = 32; off > 0; off >>= 1) {
        sum += __shfl_down(sum, off);
        sq  += __shfl_down(sq, off);
    }
    int wave = tid >> 6, lane = tid & 63;
    if (lane == 0) { s1[wave] = sum; s2[wave] = sq; }
    __syncthreads();
    float tot = s1[0] + s1[1] + s1[2] + s1[3];
    float totsq = s2[0] + s2[1] + s2[2] + s2[3];
    float mu = tot * (1.f / DDIM);
    float var = totsq * (1.f / DDIM) - mu * mu;
    float rs = rsqrtf(var + 1e-5f);
    float4 gv = ((const float4*)g)[tid];
    float4 bv = ((const float4*)b)[tid];
    float4 o;
    o.x = (v.x - mu) * rs * gv.x + bv.x;
    o.y = (v.y - mu) * rs * gv.y + bv.y;
    o.z = (v.z - mu) * rs * gv.z + bv.z;
    o.w = (v.w - mu) * rs * gv.w + bv.w;
    ((float4*)row)[tid] = o;
}

extern "C" void kernel_launch(void* const* d_in, const int* in_sizes, int n_in,
                              void* d_out, int out_size, void* d_ws, size_t ws_size,
                              hipStream_t stream) {
    const float* x   = (const float*)d_in[0];
    const float* rw  = (const float*)d_in[1];
    const float* wfc = (const float*)d_in[2];
    const float* bfc = (const float*)d_in[3];
    const float* wpr = (const float*)d_in[4];
    const float* bpr = (const float*)d_in[5];
    const float* lng = (const float*)d_in[6];
    const float* lnb = (const float*)d_in[7];

    float* out = (float*)d_out;                       // [16384,1024]
    float* logits = out + (size_t)NTOK * DDIM;        // [16384,8]

    char* ws = (char*)d_ws;
    unsigned short* xb     = (unsigned short*)(ws + WS_XB);
    unsigned short* wfcb   = (unsigned short*)(ws + WS_WFCB);
    unsigned short* wprojb = (unsigned short*)(ws + WS_WPROJB);
    unsigned short* hbuf   = (unsigned short*)(ws + WS_H);

    // Pick the largest chunk size (h tiles) that fits in ws. ws_size is fixed
    // across calls, so this branch is graph-capture safe. All ct % 8 == 0
    // (required by gemm2's XCD-grouped remap bijection).
    size_t aux_bytes = (size_t)PADPAIRS * 8 + (size_t)NTOK * 16 + 16384;
    int ct = 72;                                      // fallback (4 chunks)
    if (ws_size >= WS_H + (size_t)264 * 128 * FDIM * 2 + aux_bytes)      ct = 264;
    else if (ws_size >= WS_H + (size_t)136 * 128 * FDIM * 2 + aux_bytes) ct = 136;
    int nchunks = (MAXTILES + ct - 1) / ct;

    char* aux = ws + WS_H + (size_t)ct * 128 * FDIM * 2;
    int*   ptok  = (int*)aux;
    float* pgate = (float*)(aux + (size_t)PADPAIRS * 4);
    int*   tidx  = (int*)(aux + (size_t)PADPAIRS * 8);
    float* tgate = (float*)(aux + (size_t)PADPAIRS * 8 + (size_t)NTOK * 8);
    int*   meta  = (int*)(aux + (size_t)PADPAIRS * 8 + (size_t)NTOK * 16);
    // meta layout (ints): counts[0..127] stride16, cursor[128..255] stride16,
    // segs[256..263], total[264], tile2e[272..272+TILE2E_PAD)
    int* counts = meta;           // padded, counts[e*16]
    int* cursor = meta + 128;     // padded, cursor[e*16]
    int* segs   = meta + 256;     // 8
    int* total  = meta + 264;     // 1
    int* tile2e = meta + 272;     // TILE2E_PAD

    hipMemsetAsync(out, 0, (size_t)NTOK * DDIM * sizeof(float), stream);
    hipMemsetAsync(meta, 0, 2048, stream);

    convert_kernel<<<(NEXP * FDIM * DDIM) / 4 / 256, 256, 0, stream>>>(wfc, wfcb);
    convert_kernel<<<(NEXP * DDIM * FDIM) / 4 / 256, 256, 0, stream>>>(wpr, wprojb);
    router_kernel<<<NTOK / 16, 256, 0, stream>>>(x, rw, xb, logits, tidx, tgate, counts);
    seg_plan<<<1, 256, 0, stream>>>(counts, segs, tile2e, total, ptok, pgate);
    scatter_k<<<NTOK / 256, 256, 0, stream>>>(tidx, tgate, segs, cursor, ptok, pgate);

    for (int c = 0; c < nchunks; c++) {
        gemm1_kernel<<<dim3(FDIM / 128, ct), 256, 0, stream>>>(
            xb, wfcb, bfc, ptok, tile2e, c * ct, hbuf);
        gemm2_kernel<<<dim3(8, ct), 256, 0, stream>>>(
            hbuf, wprojb, bpr, ptok, pgate, tile2e, c * ct, out);
    }
    ln_kernel<<<NTOK, 256, 0, stream>>>(out, lng, lnb);
}